// Round 11
// baseline (572.847 us; speedup 1.0000x reference)
//
#include <hip/hip_runtime.h>
#include <hip/hip_bf16.h>

typedef __attribute__((ext_vector_type(8))) short short8v;
typedef __attribute__((ext_vector_type(4))) float f32x4;

__device__ inline float b2f(ushort u) {
  union { uint i; float f; } c;
  c.i = (uint)u << 16;
  return c.f;
}
__device__ inline ushort f2b(float f) {
  __hip_bfloat16 h = __float2bfloat16(f);
  return *(ushort*)&h;
}

typedef __attribute__((address_space(1))) const unsigned int guint;
typedef __attribute__((address_space(3))) unsigned int luint;
__device__ __forceinline__ void gload16(const void* g, void* l) {
  __builtin_amdgcn_global_load_lds((guint*)g, (luint*)l, 16, 0, 0);
}

// ===== MLP MFMA GEMM: A fp32 reg-staged (+BN fold), B via global_load_lds ====
// C = act(A)[M,K] @ B[N,Kp]^T, partials P[z][M][N]. grid = nc*nr*nz (%8==0).
template <bool BN, bool ALIGNED>
__global__ __launch_bounds__(256) void gemm_bn(
    const float* __restrict__ A, const __hip_bfloat16* __restrict__ Bh,
    const __hip_bfloat16* __restrict__ Bl, const float* __restrict__ sc,
    const float* __restrict__ sh, float* __restrict__ P, int M, int N, int K,
    int Kp, int nc, int nr, int nz) {
  __shared__ ushort Ash[128][40];
  __shared__ ushort Asl[128][40];
  __shared__ ushort Bs2[128][32];   // linear: global_load_lds dest (hi)
  __shared__ ushort Bl2[128][32];   // linear: global_load_lds dest (lo)
  const int nwg = gridDim.x;
  const int b = blockIdx.x;
  const int l = (b & 7) * (nwg >> 3) + (b >> 3);
  const int cb = l % nc;
  const int rr = (l / nc) % nr;
  const int z = l / (nc * nr);

  const int tid = threadIdx.x;
  const int lane = tid & 63;
  const int w = tid >> 6, wr = w >> 1, wc = w & 1;
  const int brow = rr * 128, bcol = cb * 128;
  const int l15 = lane & 15, koff = (lane >> 4) * 8;
  const int arow = tid >> 1, aseg = (tid & 1) * 16;
  const int srow = tid >> 2, sseg = (tid & 3) * 8;  // B staging chunk
  const int nK = (K + 31) >> 5;
  const int ks0 = (nK * z) / nz, ks1 = (nK * (z + 1)) / nz;

  f32x4 acc[4][4] = {};

  const int ar = brow + arow;
  const bool arv = ar < M;
  const float* Arow = A + (long)ar * K;
  const ushort* gBh0 = (const ushort*)Bh + (long)(bcol + srow) * Kp + sseg;
  const ushort* gBh1 = (const ushort*)Bh + (long)(bcol + 64 + srow) * Kp + sseg;
  const ushort* gBl0 = (const ushort*)Bl + (long)(bcol + srow) * Kp + sseg;
  const ushort* gBl1 = (const ushort*)Bl + (long)(bcol + 64 + srow) * Kp + sseg;
  ushort* lBh0 = &Bs2[0][0] + ((w * 64) << 3);
  ushort* lBh1 = &Bs2[0][0] + ((256 + w * 64) << 3);
  ushort* lBl0 = &Bl2[0][0] + ((w * 64) << 3);
  ushort* lBl1 = &Bl2[0][0] + ((256 + w * 64) << 3);

  for (int ks = ks0; ks < ks1; ++ks) {
    const int k0 = ks << 5;
    const int kbase = k0 + aseg;
    float av[16];
    if (arv) {
      if (ALIGNED) {
        const float4* ap = (const float4*)(Arow + kbase);
#pragma unroll
        for (int q = 0; q < 4; ++q) {
          float4 f = ap[q];
          av[q * 4 + 0] = f.x;
          av[q * 4 + 1] = f.y;
          av[q * 4 + 2] = f.z;
          av[q * 4 + 3] = f.w;
        }
      } else {
        if (kbase + 16 <= K) {
#pragma unroll
          for (int j = 0; j < 16; ++j) av[j] = Arow[kbase + j];
        } else {
#pragma unroll
          for (int j = 0; j < 16; ++j)
            av[j] = (kbase + j < K) ? Arow[kbase + j] : 0.f;
        }
      }
      if (BN) {
#pragma unroll
        for (int q = 0; q < 4; ++q) {
          float4 c4 = *(const float4*)(sc + kbase + q * 4);
          float4 h4 = *(const float4*)(sh + kbase + q * 4);
          float* a4 = &av[q * 4];
          a4[0] = fmaf(a4[0], c4.x, h4.x);
          a4[1] = fmaf(a4[1], c4.y, h4.y);
          a4[2] = fmaf(a4[2], c4.z, h4.z);
          a4[3] = fmaf(a4[3], c4.w, h4.w);
        }
#pragma unroll
        for (int j = 0; j < 16; ++j) {
          float v = av[j];
          av[j] = v > 0.f ? v : (__expf(v) - 1.f);
        }
      }
    } else {
#pragma unroll
      for (int j = 0; j < 16; ++j) av[j] = 0.f;
    }
    short8v ah0, ah1, al0, al1;
#pragma unroll
    for (int j = 0; j < 8; ++j) {
      {
        uint u = __float_as_uint(av[j]);
        ah0[j] = (short)(u >> 16);
        al0[j] = (short)f2b(av[j] - __uint_as_float(u & 0xFFFF0000u));
      }
      {
        uint u = __float_as_uint(av[j + 8]);
        ah1[j] = (short)(u >> 16);
        al1[j] = (short)f2b(av[j + 8] - __uint_as_float(u & 0xFFFF0000u));
      }
    }
    __syncthreads();  // previous iter's LDS reads complete
    // async B staging (direct to LDS) + A ds_write
    gload16(gBh0 + k0, lBh0);
    gload16(gBh1 + k0, lBh1);
    gload16(gBl0 + k0, lBl0);
    gload16(gBl1 + k0, lBl1);
    *(short8v*)&Ash[arow][aseg] = ah0;
    *(short8v*)&Ash[arow][aseg + 8] = ah1;
    *(short8v*)&Asl[arow][aseg] = al0;
    *(short8v*)&Asl[arow][aseg + 8] = al1;
    __syncthreads();  // drains vmcnt (B landed) + lgkmcnt (A landed)

    short8v bfh[4], bfl[4];
#pragma unroll
    for (int nn = 0; nn < 4; ++nn) {
      bfh[nn] = *(const short8v*)&Bs2[wc * 64 + nn * 16 + l15][koff];
      bfl[nn] = *(const short8v*)&Bl2[wc * 64 + nn * 16 + l15][koff];
    }
#pragma unroll
    for (int m = 0; m < 4; ++m) {
      short8v afh = *(const short8v*)&Ash[wr * 64 + m * 16 + l15][koff];
      short8v afl = *(const short8v*)&Asl[wr * 64 + m * 16 + l15][koff];
#pragma unroll
      for (int nn = 0; nn < 4; ++nn) {
        acc[m][nn] = __builtin_amdgcn_mfma_f32_16x16x32_bf16(afh, bfh[nn], acc[m][nn], 0, 0, 0);
        acc[m][nn] = __builtin_amdgcn_mfma_f32_16x16x32_bf16(afh, bfl[nn], acc[m][nn], 0, 0, 0);
        acc[m][nn] = __builtin_amdgcn_mfma_f32_16x16x32_bf16(afl, bfh[nn], acc[m][nn], 0, 0, 0);
      }
    }
  }

  float* outp = P + (long)z * M * N;
#pragma unroll
  for (int m = 0; m < 4; ++m) {
#pragma unroll
    for (int nn = 0; nn < 4; ++nn) {
      int col = bcol + wc * 64 + nn * 16 + l15;
#pragma unroll
      for (int r = 0; r < 4; ++r) {
        int row = brow + wr * 64 + m * 16 + (lane >> 4) * 4 + r;
        if (row < M) outp[(long)row * N + col] = acc[m][nn][r];
      }
    }
  }
}

// ===== pure bf16 MFMA GEMM (GAT layers), m97-style global_load_lds ===========
// C_b16 = A_b16 @ B_b16^T. Both operands staged direct-to-LDS (linear layout).
__global__ __launch_bounds__(256) void gemm_bf16(
    const ushort* __restrict__ A, const __hip_bfloat16* __restrict__ B,
    ushort* __restrict__ C, int M, int N, int K, int nc, int nr) {
  __shared__ ushort A2[128][32];
  __shared__ ushort B2[128][32];
  const int nwg = gridDim.x;
  const int b = blockIdx.x;
  const int l = (b & 7) * (nwg >> 3) + (b >> 3);
  const int cb = l % nc;
  const int rr = l / nc;

  const int tid = threadIdx.x;
  const int lane = tid & 63;
  const int w = tid >> 6, wr = w >> 1, wc = w & 1;
  const int brow = rr * 128, bcol = cb * 128;
  const int l15 = lane & 15, koff = (lane >> 4) * 8;
  const int srow = tid >> 2, sseg = (tid & 3) * 8;
  const int nK = K >> 5;

  f32x4 acc[4][4] = {};

  // OOB rows (brow+srow >= M) read garbage inside d_ws; they only pollute
  // C rows >= M which the epilogue discards.
  const ushort* gA0 = A + (long)(brow + srow) * K + sseg;
  const ushort* gA1 = A + (long)(brow + 64 + srow) * K + sseg;
  const ushort* gB0 = (const ushort*)B + (long)(bcol + srow) * K + sseg;
  const ushort* gB1 = (const ushort*)B + (long)(bcol + 64 + srow) * K + sseg;
  ushort* lA0 = &A2[0][0] + ((w * 64) << 3);
  ushort* lA1 = &A2[0][0] + ((256 + w * 64) << 3);
  ushort* lB0 = &B2[0][0] + ((w * 64) << 3);
  ushort* lB1 = &B2[0][0] + ((256 + w * 64) << 3);

  for (int ks = 0; ks < nK; ++ks) {
    const int k0 = ks << 5;
    __syncthreads();  // previous iter's LDS reads complete
    gload16(gA0 + k0, lA0);
    gload16(gA1 + k0, lA1);
    gload16(gB0 + k0, lB0);
    gload16(gB1 + k0, lB1);
    __syncthreads();  // vmcnt drained -> LDS populated

    short8v bf[4];
#pragma unroll
    for (int nn = 0; nn < 4; ++nn)
      bf[nn] = *(const short8v*)&B2[wc * 64 + nn * 16 + l15][koff];
#pragma unroll
    for (int m = 0; m < 4; ++m) {
      short8v af = *(const short8v*)&A2[wr * 64 + m * 16 + l15][koff];
#pragma unroll
      for (int nn = 0; nn < 4; ++nn)
        acc[m][nn] = __builtin_amdgcn_mfma_f32_16x16x32_bf16(af, bf[nn], acc[m][nn], 0, 0, 0);
    }
  }

#pragma unroll
  for (int m = 0; m < 4; ++m) {
#pragma unroll
    for (int nn = 0; nn < 4; ++nn) {
      int col = bcol + wc * 64 + nn * 16 + l15;
#pragma unroll
      for (int r = 0; r < 4; ++r) {
        int row = brow + wr * 64 + m * 16 + (lane >> 4) * 4 + r;
        if (row < M) C[(long)row * N + col] = f2b(acc[m][nn][r]);
      }
    }
  }
}

// ===== BN+ELU -> bf16 activation pass ========================================
__global__ __launch_bounds__(256) void bn_elu_b16(
    const float* __restrict__ h, const float* __restrict__ sc,
    const float* __restrict__ sh, ushort* __restrict__ o, long MN, int N) {
  long nq = MN >> 2;
  for (long q = blockIdx.x * 256LL + threadIdx.x; q < nq;
       q += (long)gridDim.x * 256LL) {
    long i = q << 2;
    int col = (int)(i % N);
    float4 v = *(const float4*)(h + i);
    float4 c = *(const float4*)(sc + col);
    float4 s = *(const float4*)(sh + col);
    float a0 = fmaf(v.x, c.x, s.x);
    float a1 = fmaf(v.y, c.y, s.y);
    float a2 = fmaf(v.z, c.z, s.z);
    float a3 = fmaf(v.w, c.w, s.w);
    a0 = a0 > 0.f ? a0 : (__expf(a0) - 1.f);
    a1 = a1 > 0.f ? a1 : (__expf(a1) - 1.f);
    a2 = a2 > 0.f ? a2 : (__expf(a2) - 1.f);
    a3 = a3 > 0.f ? a3 : (__expf(a3) - 1.f);
    ushort4 r;
    r.x = f2b(a0);
    r.y = f2b(a1);
    r.z = f2b(a2);
    r.w = f2b(a3);
    *(ushort4*)(o + i) = r;
  }
}

// ===== reduce partials (+bias) (+batch stats) ================================
template <bool BIAS, bool STATS>
__global__ __launch_bounds__(256) void reduce_post(
    const float* __restrict__ P, const float* __restrict__ bias,
    float* __restrict__ C, float* __restrict__ osum, float* __restrict__ osq,
    long MN, int N, int Z) {
  const int col = (int)((blockIdx.x * 256 + threadIdx.x) % N);
  const float bv = BIAS ? bias[col] : 0.f;
  float ps = 0.f, pq = 0.f;
  for (long i = blockIdx.x * 256LL + threadIdx.x; i < MN;
       i += (long)gridDim.x * 256LL) {
    float s = bv;
    for (int zz = 0; zz < Z; ++zz) s += P[(long)zz * MN + i];
    C[i] = s;
    if (STATS) {
      ps += s;
      pq += s * s;
    }
  }
  if (STATS) {
    atomicAdd(&osum[col], ps);
    atomicAdd(&osq[col], pq);
  }
}

// ===== bn coefficients =======================================================
__global__ __launch_bounds__(256) void bn_coef(
    const float* __restrict__ ssum, const float* __restrict__ ssq,
    const float* __restrict__ g, const float* __restrict__ be,
    float* __restrict__ sc, float* __restrict__ sh, int N, float invM) {
  int c = blockIdx.x * 256 + threadIdx.x;
  if (c >= N) return;
  float mean = ssum[c] * invM;
  float var = ssq[c] * invM - mean * mean;
  float s = rsqrtf(var + 1e-5f) * g[c];
  sc[c] = s;
  sh[c] = be[c] - mean * s;
}

// ===== tiled transpose + bf16 split ==========================================
template <bool LO>
__global__ __launch_bounds__(256) void trans_split(
    const float* __restrict__ W, __hip_bfloat16* __restrict__ Oh,
    __hip_bfloat16* __restrict__ Ol, int K, int N, int Kp) {
  __shared__ float tile[64][65];
  const int k0 = blockIdx.x * 64, n0 = blockIdx.y * 64;
  const int tx = threadIdx.x & 63, ty = threadIdx.x >> 6;
#pragma unroll
  for (int j = 0; j < 16; ++j) {
    int r = ty * 16 + j;
    int k = k0 + r;
    tile[r][tx] = (k < K) ? W[(long)k * N + n0 + tx] : 0.f;
  }
  __syncthreads();
#pragma unroll
  for (int j = 0; j < 16; ++j) {
    int a = ty * 16 + j;
    float v = tile[tx][a];
    long o = (long)(n0 + a) * Kp + k0 + tx;
    if (LO) {
      uint u = __float_as_uint(v);
      ushort hu = (ushort)(u >> 16);
      Oh[o] = *(__hip_bfloat16*)&hu;
      ushort lu = f2b(v - __uint_as_float(u & 0xFFFF0000u));
      Ol[o] = *(__hip_bfloat16*)&lu;
    } else {
      ushort hu = f2b(v);
      Oh[o] = *(__hip_bfloat16*)&hu;
    }
  }
}

// ===== BatchNorm stats (for BN4 on agg) ======================================
__global__ __launch_bounds__(256) void bn_stats(
    const float* __restrict__ h, int M, int N, float* __restrict__ sum,
    float* __restrict__ sumsq) {
  int col = blockIdx.y * 256 + threadIdx.x;
  float s = 0.f, sq = 0.f;
  for (int r = blockIdx.x; r < M; r += gridDim.x) {
    float v = h[(long)r * N + col];
    s += v;
    sq += v * v;
  }
  atomicAdd(&sum[col], s);
  atomicAdd(&sumsq[col], sq);
}

// ===== GAT attention scores from bf16 features ===============================
__global__ __launch_bounds__(256) void att_scores_bf16(
    const ushort* __restrict__ hgb, const float* __restrict__ att_s,
    const float* __restrict__ att_d, float* __restrict__ a_src,
    float* __restrict__ a_dst, int n) {
  int node = blockIdx.x;
  int h = threadIdx.x >> 6, lane = threadIdx.x & 63;
  int c = lane * 4;
  ushort4 hv = *(const ushort4*)(hgb + (long)node * 1024 + h * 256 + c);
  float4 as = *(const float4*)(att_s + h * 256 + c);
  float4 ad = *(const float4*)(att_d + h * 256 + c);
  float x0 = b2f(hv.x), x1 = b2f(hv.y), x2 = b2f(hv.z), x3 = b2f(hv.w);
  float ss = x0 * as.x + x1 * as.y + x2 * as.z + x3 * as.w;
  float sd = x0 * ad.x + x1 * ad.y + x2 * ad.z + x3 * ad.w;
#pragma unroll
  for (int off = 32; off; off >>= 1) {
    ss += __shfl_down(ss, off);
    sd += __shfl_down(sd, off);
  }
  if (lane == 0) {
    a_src[node * 4 + h] = ss;
    a_dst[node * 4 + h] = sd;
  }
}

// ===== CSR build =============================================================
__global__ __launch_bounds__(256) void deg_count(
    const int* __restrict__ srcA, const int* __restrict__ dstA,
    int* __restrict__ deg, int n, int E0, int E) {
  int e = blockIdx.x * blockDim.x + threadIdx.x;
  if (e >= E) return;
  int d;
  if (e < E0) {
    int s = srcA[e];
    d = dstA[e];
    if (s == d) d = (d + 1) % n;
  } else {
    d = e - E0;
  }
  atomicAdd(&deg[d], 1);
}

__global__ __launch_bounds__(256) void scan_rows(
    const int* __restrict__ deg, int* __restrict__ row_start, int n) {
  __shared__ int sums[256];
  int t = threadIdx.x;
  int chunk = (n + 255) / 256;
  int start = t * chunk, end = min(start + chunk, n);
  int s = 0;
  for (int i = start; i < end; ++i) s += deg[i];
  sums[t] = s;
  __syncthreads();
  for (int off = 1; off < 256; off <<= 1) {
    int v = (t >= off) ? sums[t - off] : 0;
    __syncthreads();
    sums[t] += v;
    __syncthreads();
  }
  int run = (t == 0) ? 0 : sums[t - 1];
  for (int i = start; i < end; ++i) {
    row_start[i] = run;
    run += deg[i];
  }
  if (t == 255) row_start[n] = run;
}

__global__ __launch_bounds__(256) void scatter_edges(
    const int* __restrict__ srcA, const int* __restrict__ dstA,
    int* __restrict__ cursor, int* __restrict__ csr_src, int n, int E0, int E) {
  int e = blockIdx.x * blockDim.x + threadIdx.x;
  if (e >= E) return;
  int s, d;
  if (e < E0) {
    s = srcA[e];
    d = dstA[e];
    if (s == d) d = (d + 1) % n;
  } else {
    s = d = e - E0;
  }
  int pos = atomicAdd(&cursor[d], 1);
  csr_src[pos] = s;
}

// ===== fused softmax + gather aggregation ====================================
__global__ __launch_bounds__(256) void aggregate_fused(
    const ushort* __restrict__ hgb, const int* __restrict__ row_start,
    const int* __restrict__ csr_src, const float* __restrict__ a_src,
    const float* __restrict__ a_dst, const float* __restrict__ bias,
    float* __restrict__ out) {
  int d = blockIdx.x;
  int t = threadIdx.x;
  int hh = t >> 6;
  int off = hh * 256 + (t & 63) * 4;
  int p0 = row_start[d], p1 = row_start[d + 1];
  float adv = a_dst[d * 4 + hh];
  float den = 1e-16f;
  float4 acc = {0.f, 0.f, 0.f, 0.f};
  for (int p = p0; p < p1; ++p) {
    int s = csr_src[p];
    float v = a_src[s * 4 + hh] + adv;
    v = v > 0.f ? v : 0.2f * v;
    float ex = __expf(v);
    den += ex;
    ushort4 hv = *(const ushort4*)(hgb + (long)s * 1024 + off);
    acc.x += ex * b2f(hv.x);
    acc.y += ex * b2f(hv.y);
    acc.z += ex * b2f(hv.z);
    acc.w += ex * b2f(hv.w);
  }
  float rden = 1.f / den;
  float4 bv = *(const float4*)(bias + off);
  float4 o;
  o.x = bv.x + acc.x * rden;
  o.y = bv.y + acc.y * rden;
  o.z = bv.z + acc.z * rden;
  o.w = bv.w + acc.w * rden;
  *(float4*)(out + (long)d * 1024 + off) = o;
}

extern "C" void kernel_launch(void* const* d_in, const int* in_sizes, int n_in,
                              void* d_out, int out_size, void* d_ws,
                              size_t ws_size, hipStream_t stream) {
  const float* x = (const float*)d_in[0];
  const int* edges = (const int*)d_in[1];
  const float* W1 = (const float*)d_in[2];
  const float* b1 = (const float*)d_in[3];
  const float* W2 = (const float*)d_in[4];
  const float* b2 = (const float*)d_in[5];
  const float* W3 = (const float*)d_in[6];
  const float* b3 = (const float*)d_in[7];
  const float* g1 = (const float*)d_in[8];
  const float* be1 = (const float*)d_in[9];
  const float* g2 = (const float*)d_in[10];
  const float* be2 = (const float*)d_in[11];
  const float* g3 = (const float*)d_in[12];
  const float* be3 = (const float*)d_in[13];
  const float* g4 = (const float*)d_in[14];
  const float* be4 = (const float*)d_in[15];
  const float* Wg1 = (const float*)d_in[16];
  const float* as1 = (const float*)d_in[17];
  const float* ad1 = (const float*)d_in[18];
  const float* bg1 = (const float*)d_in[19];
  const float* Wg2 = (const float*)d_in[20];
  const float* as2 = (const float*)d_in[21];
  const float* ad2 = (const float*)d_in[22];
  const float* bg2 = (const float*)d_in[23];
  float* out = (float*)d_out;

  const int n = 10000, E0 = 160000, E = 170000;
  const int F = 2613, Fp = 2624, D = 256, HD = 1024;
  const int* srcA = edges;
  const int* dstA = edges + E0;

  uint8_t* p = (uint8_t*)d_ws;
  auto alloc = [&](size_t bytes) -> void* {
    void* r = (void*)p;
    p += (bytes + 255) & ~(size_t)255;
    return r;
  };
  float* h1 = (float*)alloc((size_t)n * D * 4);
  float* h2 = (float*)alloc((size_t)n * D * 4);
  float* h3 = (float*)alloc((size_t)n * D * 4);
  float* agg = (float*)alloc((size_t)n * HD * 4);
  float* pbuf = (float*)alloc((size_t)8 * n * D * 4);  // Z<=8 partials
  ushort* hgb = (ushort*)alloc((size_t)n * HD * 2);    // bf16 GAT features
  ushort* actb = (ushort*)alloc((size_t)n * HD * 2);   // bf16 activations
  __hip_bfloat16* W1h = (__hip_bfloat16*)alloc((size_t)D * Fp * 2);
  __hip_bfloat16* W1l = (__hip_bfloat16*)alloc((size_t)D * Fp * 2);
  __hip_bfloat16* W2h = (__hip_bfloat16*)alloc((size_t)D * D * 2);
  __hip_bfloat16* W2l = (__hip_bfloat16*)alloc((size_t)D * D * 2);
  __hip_bfloat16* W3h = (__hip_bfloat16*)alloc((size_t)D * D * 2);
  __hip_bfloat16* W3l = (__hip_bfloat16*)alloc((size_t)D * D * 2);
  __hip_bfloat16* Wg1h = (__hip_bfloat16*)alloc((size_t)HD * D * 2);
  __hip_bfloat16* Wg2h = (__hip_bfloat16*)alloc((size_t)HD * HD * 2);
  float* asrc = (float*)alloc((size_t)n * 4 * 4);
  float* adst = (float*)alloc((size_t)n * 4 * 4);
  float* sc1 = (float*)alloc(D * 4);
  float* sh1 = (float*)alloc(D * 4);
  float* sc2 = (float*)alloc(D * 4);
  float* sh2 = (float*)alloc(D * 4);
  float* sc3 = (float*)alloc(D * 4);
  float* sh3 = (float*)alloc(D * 4);
  float* sc4 = (float*)alloc(HD * 4);
  float* sh4 = (float*)alloc(HD * 4);
  int* row_start = (int*)alloc((size_t)(n + 1) * 4);
  int* cursor = (int*)alloc((size_t)n * 4);
  int* csr_src = (int*)alloc((size_t)E * 4);
  // ---- contiguous zero block (stats + deg) ----
  uint8_t* z0 = p;
  float* ssum1 = (float*)alloc(D * 4);
  float* ssq1 = (float*)alloc(D * 4);
  float* ssum2 = (float*)alloc(D * 4);
  float* ssq2 = (float*)alloc(D * 4);
  float* ssum3 = (float*)alloc(D * 4);
  float* ssq3 = (float*)alloc(D * 4);
  float* ssum4 = (float*)alloc(HD * 4);
  float* ssq4 = (float*)alloc(HD * 4);
  int* deg = (int*)alloc((size_t)n * 4);
  size_t zbytes = (size_t)(p - z0);

  dim3 blk(256);
  const int rb = (n + 127) / 128;  // 79
  const int eb = (E + 255) / 256;
  const long MN_D = (long)n * D;
  const long MN_HD = (long)n * HD;
  const float invM = 1.f / (float)n;
  const int gL1 = 2 * rb * 8;   // 1264 (Z=8)
  const int gMLP = 2 * rb * 4;  // 632  (Z=4)
  const int gGAT = 8 * rb;      // 632

  hipMemsetAsync(z0, 0, zbytes, stream);

  // ---- CSR build ----
  deg_count<<<eb, blk, 0, stream>>>(srcA, dstA, deg, n, E0, E);
  scan_rows<<<1, blk, 0, stream>>>(deg, row_start, n);
  hipMemcpyAsync(cursor, row_start, n * sizeof(int), hipMemcpyDeviceToDevice, stream);
  scatter_edges<<<eb, blk, 0, stream>>>(srcA, dstA, cursor, csr_src, n, E0, E);

  // ---- weight transpose+split ----
  trans_split<true><<<dim3(Fp / 64, D / 64), blk, 0, stream>>>(W1, W1h, W1l, F, D, Fp);
  trans_split<true><<<dim3(D / 64, D / 64), blk, 0, stream>>>(W2, W2h, W2l, D, D, D);
  trans_split<true><<<dim3(D / 64, D / 64), blk, 0, stream>>>(W3, W3h, W3l, D, D, D);
  trans_split<false><<<dim3(D / 64, HD / 64), blk, 0, stream>>>(Wg1, Wg1h, nullptr, D, HD, D);
  trans_split<false><<<dim3(HD / 64, HD / 64), blk, 0, stream>>>(Wg2, Wg2h, nullptr, HD, HD, HD);

  // ---- MLP layer 1: h1 = x@W1 + b1 (raw); stats1  [3-term, Z=8] ----
  gemm_bn<false, false><<<gL1, blk, 0, stream>>>(
      x, W1h, W1l, nullptr, nullptr, pbuf, n, D, F, Fp, 2, rb, 8);
  reduce_post<true, true><<<512, blk, 0, stream>>>(pbuf, b1, h1, ssum1, ssq1, MN_D, D, 8);
  bn_coef<<<1, blk, 0, stream>>>(ssum1, ssq1, g1, be1, sc1, sh1, D, invM);

  // ---- MLP layer 2  [3-term, Z=4, BN1 fused] ----
  gemm_bn<true, true><<<gMLP, blk, 0, stream>>>(
      h1, W2h, W2l, sc1, sh1, pbuf, n, D, D, D, 2, rb, 4);
  reduce_post<true, true><<<512, blk, 0, stream>>>(pbuf, b2, h2, ssum2, ssq2, MN_D, D, 4);
  bn_coef<<<1, blk, 0, stream>>>(ssum2, ssq2, g2, be2, sc2, sh2, D, invM);

  // ---- MLP layer 3  [3-term, Z=4, BN2 fused] ----
  gemm_bn<true, true><<<gMLP, blk, 0, stream>>>(
      h2, W3h, W3l, sc2, sh2, pbuf, n, D, D, D, 2, rb, 4);
  reduce_post<true, true><<<512, blk, 0, stream>>>(pbuf, b3, h3, ssum3, ssq3, MN_D, D, 4);
  bn_coef<<<1, blk, 0, stream>>>(ssum3, ssq3, g3, be3, sc3, sh3, D, invM);

  // ---- GAT layer 1: act3 = bf16(elu(bn3(h3))); hgb = act3 @ Wg1 ----
  bn_elu_b16<<<1024, blk, 0, stream>>>(h3, sc3, sh3, actb, MN_D, D);
  gemm_bf16<<<gGAT, blk, 0, stream>>>(actb, Wg1h, hgb, n, HD, D, 8, rb);
  att_scores_bf16<<<n, blk, 0, stream>>>(hgb, as1, ad1, asrc, adst, n);
  aggregate_fused<<<n, blk, 0, stream>>>(hgb, row_start, csr_src, asrc, adst, bg1, agg);

  // ---- BN4 stats + coef + activation ----
  bn_stats<<<dim3(64, HD / 256), blk, 0, stream>>>(agg, n, HD, ssum4, ssq4);
  bn_coef<<<4, blk, 0, stream>>>(ssum4, ssq4, g4, be4, sc4, sh4, HD, invM);
  bn_elu_b16<<<2048, blk, 0, stream>>>(agg, sc4, sh4, actb, MN_HD, HD);

  // ---- GAT layer 2: hgb = act4 @ Wg2; out = aggregate + bg2 ----
  gemm_bf16<<<gGAT, blk, 0, stream>>>(actb, Wg2h, hgb, n, HD, HD, 8, rb);
  att_scores_bf16<<<n, blk, 0, stream>>>(hgb, as2, ad2, asrc, adst, n);
  aggregate_fused<<<n, blk, 0, stream>>>(hgb, row_start, csr_src, asrc, adst, bg2, out);
}

// Round 12
// 560.917 us; speedup vs baseline: 1.0213x; 1.0213x over previous
//
#include <hip/hip_runtime.h>
#include <hip/hip_bf16.h>

typedef __attribute__((ext_vector_type(8))) short short8v;
typedef __attribute__((ext_vector_type(4))) float f32x4;

__device__ inline float b2f(ushort u) {
  union { uint i; float f; } c;
  c.i = (uint)u << 16;
  return c.f;
}
__device__ inline ushort f2b(float f) {
  __hip_bfloat16 h = __float2bfloat16(f);
  return *(ushort*)&h;
}

typedef __attribute__((address_space(1))) const unsigned int guint;
typedef __attribute__((address_space(3))) unsigned int luint;
__device__ __forceinline__ void gload16(const void* g, void* l) {
  __builtin_amdgcn_global_load_lds((guint*)g, (luint*)l, 16, 0, 0);
}

// ===== MLP MFMA GEMM: A fp32 reg-prefetched (+BN fold), B dbuf gload_lds =====
// C = act(A)[M,K] @ B[N,Kp]^T, partials P[z][M][N]. grid = nc*nr*nz (%8==0).
// Pipeline: A(ks+1) reg loads and B(ks+1) global_load_lds are issued AFTER
// bar2 of iter ks, draining at bar1 of iter ks+1 -> full MFMA phase in flight.
template <bool BN, bool ALIGNED>
__global__ __launch_bounds__(256) void gemm_bn(
    const float* __restrict__ A, const __hip_bfloat16* __restrict__ Bh,
    const __hip_bfloat16* __restrict__ Bl, const float* __restrict__ sc,
    const float* __restrict__ sh, float* __restrict__ P, int M, int N, int K,
    int Kp, int nc, int nr, int nz) {
  __shared__ ushort Ash[128][40];
  __shared__ ushort Asl[128][40];
  __shared__ ushort Bs2[2][128][32];  // hi, double-buffered (gload_lds dest)
  __shared__ ushort Bl2[2][128][32];  // lo, double-buffered
  const int nwg = gridDim.x;
  const int b = blockIdx.x;
  const int l = (b & 7) * (nwg >> 3) + (b >> 3);
  const int cb = l % nc;
  const int rr = (l / nc) % nr;
  const int z = l / (nc * nr);

  const int tid = threadIdx.x;
  const int lane = tid & 63;
  const int w = tid >> 6, wr = w >> 1, wc = w & 1;
  const int brow = rr * 128, bcol = cb * 128;
  const int l15 = lane & 15, koff = (lane >> 4) * 8;
  const int arow = tid >> 1, aseg = (tid & 1) * 16;
  const int srow = tid >> 2, sseg = (tid & 3) * 8;
  const int nK = (K + 31) >> 5;
  const int ks0 = (nK * z) / nz, ks1 = (nK * (z + 1)) / nz;

  f32x4 acc[4][4] = {};

  const int ar = brow + arow;
  const bool arv = ar < M;
  const float* Arow = A + (long)ar * K;
  const ushort* gBh0 = (const ushort*)Bh + (long)(bcol + srow) * Kp + sseg;
  const ushort* gBh1 = (const ushort*)Bh + (long)(bcol + 64 + srow) * Kp + sseg;
  const ushort* gBl0 = (const ushort*)Bl + (long)(bcol + srow) * Kp + sseg;
  const ushort* gBl1 = (const ushort*)Bl + (long)(bcol + 64 + srow) * Kp + sseg;
  const int lo0 = (w * 64) << 3;        // ushort offset in a [128][32] buffer
  const int lo1 = (256 + w * 64) << 3;

  float av[16];
  auto loadAv = [&](int ks) {
    const int kb = (ks << 5) + aseg;
    if (arv) {
      if (ALIGNED) {
        const float4* ap = (const float4*)(Arow + kb);
#pragma unroll
        for (int q = 0; q < 4; ++q) {
          float4 f = ap[q];
          av[q * 4 + 0] = f.x;
          av[q * 4 + 1] = f.y;
          av[q * 4 + 2] = f.z;
          av[q * 4 + 3] = f.w;
        }
      } else {
        if (kb + 16 <= K) {
#pragma unroll
          for (int j = 0; j < 16; ++j) av[j] = Arow[kb + j];
        } else {
#pragma unroll
          for (int j = 0; j < 16; ++j) av[j] = (kb + j < K) ? Arow[kb + j] : 0.f;
        }
      }
    } else {
#pragma unroll
      for (int j = 0; j < 16; ++j) av[j] = 0.f;
    }
  };

  if (ks0 < ks1) {
    loadAv(ks0);
    const int k0 = ks0 << 5;
    gload16(gBh0 + k0, &Bs2[0][0][0] + lo0);
    gload16(gBh1 + k0, &Bs2[0][0][0] + lo1);
    gload16(gBl0 + k0, &Bl2[0][0][0] + lo0);
    gload16(gBl1 + k0, &Bl2[0][0][0] + lo1);
  }

  for (int ks = ks0; ks < ks1; ++ks) {
    const int cur = (ks - ks0) & 1;
    const int kbase = (ks << 5) + aseg;
    // ---- BN + ELU on current av (prefetched) ----
    if (BN && arv) {
#pragma unroll
      for (int q = 0; q < 4; ++q) {
        float4 c4 = *(const float4*)(sc + kbase + q * 4);
        float4 h4 = *(const float4*)(sh + kbase + q * 4);
        float* a4 = &av[q * 4];
        a4[0] = fmaf(a4[0], c4.x, h4.x);
        a4[1] = fmaf(a4[1], c4.y, h4.y);
        a4[2] = fmaf(a4[2], c4.z, h4.z);
        a4[3] = fmaf(a4[3], c4.w, h4.w);
      }
#pragma unroll
      for (int j = 0; j < 16; ++j) {
        float v = av[j];
        av[j] = v > 0.f ? v : (__expf(v) - 1.f);
      }
    }
    short8v ah0, ah1, al0, al1;
#pragma unroll
    for (int j = 0; j < 8; ++j) {
      {
        uint u = __float_as_uint(av[j]);
        ah0[j] = (short)(u >> 16);
        al0[j] = (short)f2b(av[j] - __uint_as_float(u & 0xFFFF0000u));
      }
      {
        uint u = __float_as_uint(av[j + 8]);
        ah1[j] = (short)(u >> 16);
        al1[j] = (short)f2b(av[j + 8] - __uint_as_float(u & 0xFFFF0000u));
      }
    }
    __syncthreads();  // bar1: B(cur) landed (issued prev iter); prev reads done
    *(short8v*)&Ash[arow][aseg] = ah0;
    *(short8v*)&Ash[arow][aseg + 8] = ah1;
    *(short8v*)&Asl[arow][aseg] = al0;
    *(short8v*)&Asl[arow][aseg + 8] = al1;
    __syncthreads();  // bar2: A visible
    if (ks + 1 < ks1) {  // issue next-iter loads; drain at next bar1
      const int k0n = (ks + 1) << 5;
      const int nxt = cur ^ 1;
      ushort* bh = &Bs2[nxt][0][0];
      ushort* bl = &Bl2[nxt][0][0];
      gload16(gBh0 + k0n, bh + lo0);
      gload16(gBh1 + k0n, bh + lo1);
      gload16(gBl0 + k0n, bl + lo0);
      gload16(gBl1 + k0n, bl + lo1);
      loadAv(ks + 1);
    }
    short8v bfh[4], bfl[4];
#pragma unroll
    for (int nn = 0; nn < 4; ++nn) {
      bfh[nn] = *(const short8v*)&Bs2[cur][wc * 64 + nn * 16 + l15][koff];
      bfl[nn] = *(const short8v*)&Bl2[cur][wc * 64 + nn * 16 + l15][koff];
    }
#pragma unroll
    for (int m = 0; m < 4; ++m) {
      short8v afh = *(const short8v*)&Ash[wr * 64 + m * 16 + l15][koff];
      short8v afl = *(const short8v*)&Asl[wr * 64 + m * 16 + l15][koff];
#pragma unroll
      for (int nn = 0; nn < 4; ++nn) {
        acc[m][nn] = __builtin_amdgcn_mfma_f32_16x16x32_bf16(afh, bfh[nn], acc[m][nn], 0, 0, 0);
        acc[m][nn] = __builtin_amdgcn_mfma_f32_16x16x32_bf16(afh, bfl[nn], acc[m][nn], 0, 0, 0);
        acc[m][nn] = __builtin_amdgcn_mfma_f32_16x16x32_bf16(afl, bfh[nn], acc[m][nn], 0, 0, 0);
      }
    }
  }

  float* outp = P + (long)z * M * N;
#pragma unroll
  for (int m = 0; m < 4; ++m) {
#pragma unroll
    for (int nn = 0; nn < 4; ++nn) {
      int col = bcol + wc * 64 + nn * 16 + l15;
#pragma unroll
      for (int r = 0; r < 4; ++r) {
        int row = brow + wr * 64 + m * 16 + (lane >> 4) * 4 + r;
        if (row < M) outp[(long)row * N + col] = acc[m][nn][r];
      }
    }
  }
}

// ===== pure bf16 MFMA GEMM (GAT layers), single-barrier double-buffer ========
// C_b16 = A_b16 @ B_b16^T. Loads for iter ks+1 issued right after the barrier
// of iter ks -> in flight across the whole MFMA phase (drained at next barrier).
__global__ __launch_bounds__(256) void gemm_bf16(
    const ushort* __restrict__ A, const __hip_bfloat16* __restrict__ B,
    ushort* __restrict__ C, int M, int N, int K, int nc, int nr) {
  __shared__ ushort A2[2][128][32];
  __shared__ ushort B2[2][128][32];
  const int nwg = gridDim.x;
  const int b = blockIdx.x;
  const int l = (b & 7) * (nwg >> 3) + (b >> 3);
  const int cb = l % nc;
  const int rr = l / nc;

  const int tid = threadIdx.x;
  const int lane = tid & 63;
  const int w = tid >> 6, wr = w >> 1, wc = w & 1;
  const int brow = rr * 128, bcol = cb * 128;
  const int l15 = lane & 15, koff = (lane >> 4) * 8;
  const int srow = tid >> 2, sseg = (tid & 3) * 8;
  const int nK = K >> 5;

  f32x4 acc[4][4] = {};

  // OOB rows (brow+srow >= M) read garbage inside d_ws; they only pollute
  // C rows >= M which the epilogue discards.
  const ushort* gA0 = A + (long)(brow + srow) * K + sseg;
  const ushort* gA1 = A + (long)(brow + 64 + srow) * K + sseg;
  const ushort* gB0 = (const ushort*)B + (long)(bcol + srow) * K + sseg;
  const ushort* gB1 = (const ushort*)B + (long)(bcol + 64 + srow) * K + sseg;
  const int lo0 = (w * 64) << 3;
  const int lo1 = (256 + w * 64) << 3;

  // prologue: stage K-step 0 into buffer 0
  gload16(gA0, &A2[0][0][0] + lo0);
  gload16(gA1, &A2[0][0][0] + lo1);
  gload16(gB0, &B2[0][0][0] + lo0);
  gload16(gB1, &B2[0][0][0] + lo1);

  for (int ks = 0; ks < nK; ++ks) {
    const int cur = ks & 1;
    __syncthreads();  // buf[cur] fully landed; prev iter's reads of buf[cur^1] done
    if (ks + 1 < nK) {
      const int k0n = (ks + 1) << 5;
      const int nxt = cur ^ 1;
      gload16(gA0 + k0n, &A2[nxt][0][0] + lo0);
      gload16(gA1 + k0n, &A2[nxt][0][0] + lo1);
      gload16(gB0 + k0n, &B2[nxt][0][0] + lo0);
      gload16(gB1 + k0n, &B2[nxt][0][0] + lo1);
    }
    short8v bf[4];
#pragma unroll
    for (int nn = 0; nn < 4; ++nn)
      bf[nn] = *(const short8v*)&B2[cur][wc * 64 + nn * 16 + l15][koff];
#pragma unroll
    for (int m = 0; m < 4; ++m) {
      short8v af = *(const short8v*)&A2[cur][wr * 64 + m * 16 + l15][koff];
#pragma unroll
      for (int nn = 0; nn < 4; ++nn)
        acc[m][nn] = __builtin_amdgcn_mfma_f32_16x16x32_bf16(af, bf[nn], acc[m][nn], 0, 0, 0);
    }
  }

#pragma unroll
  for (int m = 0; m < 4; ++m) {
#pragma unroll
    for (int nn = 0; nn < 4; ++nn) {
      int col = bcol + wc * 64 + nn * 16 + l15;
#pragma unroll
      for (int r = 0; r < 4; ++r) {
        int row = brow + wr * 64 + m * 16 + (lane >> 4) * 4 + r;
        if (row < M) C[(long)row * N + col] = f2b(acc[m][nn][r]);
      }
    }
  }
}

// ===== BN+ELU -> bf16 activation pass ========================================
__global__ __launch_bounds__(256) void bn_elu_b16(
    const float* __restrict__ h, const float* __restrict__ sc,
    const float* __restrict__ sh, ushort* __restrict__ o, long MN, int N) {
  long nq = MN >> 2;
  for (long q = blockIdx.x * 256LL + threadIdx.x; q < nq;
       q += (long)gridDim.x * 256LL) {
    long i = q << 2;
    int col = (int)(i % N);
    float4 v = *(const float4*)(h + i);
    float4 c = *(const float4*)(sc + col);
    float4 s = *(const float4*)(sh + col);
    float a0 = fmaf(v.x, c.x, s.x);
    float a1 = fmaf(v.y, c.y, s.y);
    float a2 = fmaf(v.z, c.z, s.z);
    float a3 = fmaf(v.w, c.w, s.w);
    a0 = a0 > 0.f ? a0 : (__expf(a0) - 1.f);
    a1 = a1 > 0.f ? a1 : (__expf(a1) - 1.f);
    a2 = a2 > 0.f ? a2 : (__expf(a2) - 1.f);
    a3 = a3 > 0.f ? a3 : (__expf(a3) - 1.f);
    ushort4 r;
    r.x = f2b(a0);
    r.y = f2b(a1);
    r.z = f2b(a2);
    r.w = f2b(a3);
    *(ushort4*)(o + i) = r;
  }
}

// ===== reduce partials (+bias) (+batch stats) ================================
template <bool BIAS, bool STATS>
__global__ __launch_bounds__(256) void reduce_post(
    const float* __restrict__ P, const float* __restrict__ bias,
    float* __restrict__ C, float* __restrict__ osum, float* __restrict__ osq,
    long MN, int N, int Z) {
  const int col = (int)((blockIdx.x * 256 + threadIdx.x) % N);
  const float bv = BIAS ? bias[col] : 0.f;
  float ps = 0.f, pq = 0.f;
  for (long i = blockIdx.x * 256LL + threadIdx.x; i < MN;
       i += (long)gridDim.x * 256LL) {
    float s = bv;
    for (int zz = 0; zz < Z; ++zz) s += P[(long)zz * MN + i];
    C[i] = s;
    if (STATS) {
      ps += s;
      pq += s * s;
    }
  }
  if (STATS) {
    atomicAdd(&osum[col], ps);
    atomicAdd(&osq[col], pq);
  }
}

// ===== bn coefficients =======================================================
__global__ __launch_bounds__(256) void bn_coef(
    const float* __restrict__ ssum, const float* __restrict__ ssq,
    const float* __restrict__ g, const float* __restrict__ be,
    float* __restrict__ sc, float* __restrict__ sh, int N, float invM) {
  int c = blockIdx.x * 256 + threadIdx.x;
  if (c >= N) return;
  float mean = ssum[c] * invM;
  float var = ssq[c] * invM - mean * mean;
  float s = rsqrtf(var + 1e-5f) * g[c];
  sc[c] = s;
  sh[c] = be[c] - mean * s;
}

// ===== tiled transpose + bf16 split ==========================================
template <bool LO>
__global__ __launch_bounds__(256) void trans_split(
    const float* __restrict__ W, __hip_bfloat16* __restrict__ Oh,
    __hip_bfloat16* __restrict__ Ol, int K, int N, int Kp) {
  __shared__ float tile[64][65];
  const int k0 = blockIdx.x * 64, n0 = blockIdx.y * 64;
  const int tx = threadIdx.x & 63, ty = threadIdx.x >> 6;
#pragma unroll
  for (int j = 0; j < 16; ++j) {
    int r = ty * 16 + j;
    int k = k0 + r;
    tile[r][tx] = (k < K) ? W[(long)k * N + n0 + tx] : 0.f;
  }
  __syncthreads();
#pragma unroll
  for (int j = 0; j < 16; ++j) {
    int a = ty * 16 + j;
    float v = tile[tx][a];
    long o = (long)(n0 + a) * Kp + k0 + tx;
    if (LO) {
      uint u = __float_as_uint(v);
      ushort hu = (ushort)(u >> 16);
      Oh[o] = *(__hip_bfloat16*)&hu;
      ushort lu = f2b(v - __uint_as_float(u & 0xFFFF0000u));
      Ol[o] = *(__hip_bfloat16*)&lu;
    } else {
      ushort hu = f2b(v);
      Oh[o] = *(__hip_bfloat16*)&hu;
    }
  }
}

// ===== BatchNorm stats (for BN4 on agg) ======================================
__global__ __launch_bounds__(256) void bn_stats(
    const float* __restrict__ h, int M, int N, float* __restrict__ sum,
    float* __restrict__ sumsq) {
  int col = blockIdx.y * 256 + threadIdx.x;
  float s = 0.f, sq = 0.f;
  for (int r = blockIdx.x; r < M; r += gridDim.x) {
    float v = h[(long)r * N + col];
    s += v;
    sq += v * v;
  }
  atomicAdd(&sum[col], s);
  atomicAdd(&sumsq[col], sq);
}

// ===== GAT attention scores from bf16 features ===============================
__global__ __launch_bounds__(256) void att_scores_bf16(
    const ushort* __restrict__ hgb, const float* __restrict__ att_s,
    const float* __restrict__ att_d, float* __restrict__ a_src,
    float* __restrict__ a_dst, int n) {
  int node = blockIdx.x;
  int h = threadIdx.x >> 6, lane = threadIdx.x & 63;
  int c = lane * 4;
  ushort4 hv = *(const ushort4*)(hgb + (long)node * 1024 + h * 256 + c);
  float4 as = *(const float4*)(att_s + h * 256 + c);
  float4 ad = *(const float4*)(att_d + h * 256 + c);
  float x0 = b2f(hv.x), x1 = b2f(hv.y), x2 = b2f(hv.z), x3 = b2f(hv.w);
  float ss = x0 * as.x + x1 * as.y + x2 * as.z + x3 * as.w;
  float sd = x0 * ad.x + x1 * ad.y + x2 * ad.z + x3 * ad.w;
#pragma unroll
  for (int off = 32; off; off >>= 1) {
    ss += __shfl_down(ss, off);
    sd += __shfl_down(sd, off);
  }
  if (lane == 0) {
    a_src[node * 4 + h] = ss;
    a_dst[node * 4 + h] = sd;
  }
}

// ===== CSR build =============================================================
__global__ __launch_bounds__(256) void deg_count(
    const int* __restrict__ srcA, const int* __restrict__ dstA,
    int* __restrict__ deg, int n, int E0, int E) {
  int e = blockIdx.x * blockDim.x + threadIdx.x;
  if (e >= E) return;
  int d;
  if (e < E0) {
    int s = srcA[e];
    d = dstA[e];
    if (s == d) d = (d + 1) % n;
  } else {
    d = e - E0;
  }
  atomicAdd(&deg[d], 1);
}

__global__ __launch_bounds__(256) void scan_rows(
    const int* __restrict__ deg, int* __restrict__ row_start, int n) {
  __shared__ int sums[256];
  int t = threadIdx.x;
  int chunk = (n + 255) / 256;
  int start = t * chunk, end = min(start + chunk, n);
  int s = 0;
  for (int i = start; i < end; ++i) s += deg[i];
  sums[t] = s;
  __syncthreads();
  for (int off = 1; off < 256; off <<= 1) {
    int v = (t >= off) ? sums[t - off] : 0;
    __syncthreads();
    sums[t] += v;
    __syncthreads();
  }
  int run = (t == 0) ? 0 : sums[t - 1];
  for (int i = start; i < end; ++i) {
    row_start[i] = run;
    run += deg[i];
  }
  if (t == 255) row_start[n] = run;
}

__global__ __launch_bounds__(256) void scatter_edges(
    const int* __restrict__ srcA, const int* __restrict__ dstA,
    int* __restrict__ cursor, int* __restrict__ csr_src, int n, int E0, int E) {
  int e = blockIdx.x * blockDim.x + threadIdx.x;
  if (e >= E) return;
  int s, d;
  if (e < E0) {
    s = srcA[e];
    d = dstA[e];
    if (s == d) d = (d + 1) % n;
  } else {
    s = d = e - E0;
  }
  int pos = atomicAdd(&cursor[d], 1);
  csr_src[pos] = s;
}

// ===== fused softmax + gather aggregation ====================================
__global__ __launch_bounds__(256) void aggregate_fused(
    const ushort* __restrict__ hgb, const int* __restrict__ row_start,
    const int* __restrict__ csr_src, const float* __restrict__ a_src,
    const float* __restrict__ a_dst, const float* __restrict__ bias,
    float* __restrict__ out) {
  int d = blockIdx.x;
  int t = threadIdx.x;
  int hh = t >> 6;
  int off = hh * 256 + (t & 63) * 4;
  int p0 = row_start[d], p1 = row_start[d + 1];
  float adv = a_dst[d * 4 + hh];
  float den = 1e-16f;
  float4 acc = {0.f, 0.f, 0.f, 0.f};
  for (int p = p0; p < p1; ++p) {
    int s = csr_src[p];
    float v = a_src[s * 4 + hh] + adv;
    v = v > 0.f ? v : 0.2f * v;
    float ex = __expf(v);
    den += ex;
    ushort4 hv = *(const ushort4*)(hgb + (long)s * 1024 + off);
    acc.x += ex * b2f(hv.x);
    acc.y += ex * b2f(hv.y);
    acc.z += ex * b2f(hv.z);
    acc.w += ex * b2f(hv.w);
  }
  float rden = 1.f / den;
  float4 bv = *(const float4*)(bias + off);
  float4 o;
  o.x = bv.x + acc.x * rden;
  o.y = bv.y + acc.y * rden;
  o.z = bv.z + acc.z * rden;
  o.w = bv.w + acc.w * rden;
  *(float4*)(out + (long)d * 1024 + off) = o;
}

extern "C" void kernel_launch(void* const* d_in, const int* in_sizes, int n_in,
                              void* d_out, int out_size, void* d_ws,
                              size_t ws_size, hipStream_t stream) {
  const float* x = (const float*)d_in[0];
  const int* edges = (const int*)d_in[1];
  const float* W1 = (const float*)d_in[2];
  const float* b1 = (const float*)d_in[3];
  const float* W2 = (const float*)d_in[4];
  const float* b2 = (const float*)d_in[5];
  const float* W3 = (const float*)d_in[6];
  const float* b3 = (const float*)d_in[7];
  const float* g1 = (const float*)d_in[8];
  const float* be1 = (const float*)d_in[9];
  const float* g2 = (const float*)d_in[10];
  const float* be2 = (const float*)d_in[11];
  const float* g3 = (const float*)d_in[12];
  const float* be3 = (const float*)d_in[13];
  const float* g4 = (const float*)d_in[14];
  const float* be4 = (const float*)d_in[15];
  const float* Wg1 = (const float*)d_in[16];
  const float* as1 = (const float*)d_in[17];
  const float* ad1 = (const float*)d_in[18];
  const float* bg1 = (const float*)d_in[19];
  const float* Wg2 = (const float*)d_in[20];
  const float* as2 = (const float*)d_in[21];
  const float* ad2 = (const float*)d_in[22];
  const float* bg2 = (const float*)d_in[23];
  float* out = (float*)d_out;

  const int n = 10000, E0 = 160000, E = 170000;
  const int F = 2613, Fp = 2624, D = 256, HD = 1024;
  const int* srcA = edges;
  const int* dstA = edges + E0;

  uint8_t* p = (uint8_t*)d_ws;
  auto alloc = [&](size_t bytes) -> void* {
    void* r = (void*)p;
    p += (bytes + 255) & ~(size_t)255;
    return r;
  };
  float* h1 = (float*)alloc((size_t)n * D * 4);
  float* h2 = (float*)alloc((size_t)n * D * 4);
  float* h3 = (float*)alloc((size_t)n * D * 4);
  float* agg = (float*)alloc((size_t)n * HD * 4);
  float* pbuf = (float*)alloc((size_t)8 * n * D * 4);  // Z<=8 partials
  ushort* hgb = (ushort*)alloc((size_t)n * HD * 2);    // bf16 GAT features
  ushort* actb = (ushort*)alloc((size_t)n * HD * 2);   // bf16 activations
  __hip_bfloat16* W1h = (__hip_bfloat16*)alloc((size_t)D * Fp * 2);
  __hip_bfloat16* W1l = (__hip_bfloat16*)alloc((size_t)D * Fp * 2);
  __hip_bfloat16* W2h = (__hip_bfloat16*)alloc((size_t)D * D * 2);
  __hip_bfloat16* W2l = (__hip_bfloat16*)alloc((size_t)D * D * 2);
  __hip_bfloat16* W3h = (__hip_bfloat16*)alloc((size_t)D * D * 2);
  __hip_bfloat16* W3l = (__hip_bfloat16*)alloc((size_t)D * D * 2);
  __hip_bfloat16* Wg1h = (__hip_bfloat16*)alloc((size_t)HD * D * 2);
  __hip_bfloat16* Wg2h = (__hip_bfloat16*)alloc((size_t)HD * HD * 2);
  float* asrc = (float*)alloc((size_t)n * 4 * 4);
  float* adst = (float*)alloc((size_t)n * 4 * 4);
  float* sc1 = (float*)alloc(D * 4);
  float* sh1 = (float*)alloc(D * 4);
  float* sc2 = (float*)alloc(D * 4);
  float* sh2 = (float*)alloc(D * 4);
  float* sc3 = (float*)alloc(D * 4);
  float* sh3 = (float*)alloc(D * 4);
  float* sc4 = (float*)alloc(HD * 4);
  float* sh4 = (float*)alloc(HD * 4);
  int* row_start = (int*)alloc((size_t)(n + 1) * 4);
  int* cursor = (int*)alloc((size_t)n * 4);
  int* csr_src = (int*)alloc((size_t)E * 4);
  // ---- contiguous zero block (stats + deg) ----
  uint8_t* z0 = p;
  float* ssum1 = (float*)alloc(D * 4);
  float* ssq1 = (float*)alloc(D * 4);
  float* ssum2 = (float*)alloc(D * 4);
  float* ssq2 = (float*)alloc(D * 4);
  float* ssum3 = (float*)alloc(D * 4);
  float* ssq3 = (float*)alloc(D * 4);
  float* ssum4 = (float*)alloc(HD * 4);
  float* ssq4 = (float*)alloc(HD * 4);
  int* deg = (int*)alloc((size_t)n * 4);
  size_t zbytes = (size_t)(p - z0);

  dim3 blk(256);
  const int rb = (n + 127) / 128;  // 79
  const int eb = (E + 255) / 256;
  const long MN_D = (long)n * D;
  const long MN_HD = (long)n * HD;
  const float invM = 1.f / (float)n;
  const int gL1 = 2 * rb * 8;   // 1264 (Z=8)
  const int gMLP = 2 * rb * 4;  // 632  (Z=4)
  const int gGAT = 8 * rb;      // 632

  hipMemsetAsync(z0, 0, zbytes, stream);

  // ---- CSR build ----
  deg_count<<<eb, blk, 0, stream>>>(srcA, dstA, deg, n, E0, E);
  scan_rows<<<1, blk, 0, stream>>>(deg, row_start, n);
  hipMemcpyAsync(cursor, row_start, n * sizeof(int), hipMemcpyDeviceToDevice, stream);
  scatter_edges<<<eb, blk, 0, stream>>>(srcA, dstA, cursor, csr_src, n, E0, E);

  // ---- weight transpose+split ----
  trans_split<true><<<dim3(Fp / 64, D / 64), blk, 0, stream>>>(W1, W1h, W1l, F, D, Fp);
  trans_split<true><<<dim3(D / 64, D / 64), blk, 0, stream>>>(W2, W2h, W2l, D, D, D);
  trans_split<true><<<dim3(D / 64, D / 64), blk, 0, stream>>>(W3, W3h, W3l, D, D, D);
  trans_split<false><<<dim3(D / 64, HD / 64), blk, 0, stream>>>(Wg1, Wg1h, nullptr, D, HD, D);
  trans_split<false><<<dim3(HD / 64, HD / 64), blk, 0, stream>>>(Wg2, Wg2h, nullptr, HD, HD, HD);

  // ---- MLP layer 1: h1 = x@W1 + b1 (raw); stats1  [3-term, Z=8] ----
  gemm_bn<false, false><<<gL1, blk, 0, stream>>>(
      x, W1h, W1l, nullptr, nullptr, pbuf, n, D, F, Fp, 2, rb, 8);
  reduce_post<true, true><<<512, blk, 0, stream>>>(pbuf, b1, h1, ssum1, ssq1, MN_D, D, 8);
  bn_coef<<<1, blk, 0, stream>>>(ssum1, ssq1, g1, be1, sc1, sh1, D, invM);

  // ---- MLP layer 2  [3-term, Z=4, BN1 fused] ----
  gemm_bn<true, true><<<gMLP, blk, 0, stream>>>(
      h1, W2h, W2l, sc1, sh1, pbuf, n, D, D, D, 2, rb, 4);
  reduce_post<true, true><<<512, blk, 0, stream>>>(pbuf, b2, h2, ssum2, ssq2, MN_D, D, 4);
  bn_coef<<<1, blk, 0, stream>>>(ssum2, ssq2, g2, be2, sc2, sh2, D, invM);

  // ---- MLP layer 3  [3-term, Z=4, BN2 fused] ----
  gemm_bn<true, true><<<gMLP, blk, 0, stream>>>(
      h2, W3h, W3l, sc2, sh2, pbuf, n, D, D, D, 2, rb, 4);
  reduce_post<true, true><<<512, blk, 0, stream>>>(pbuf, b3, h3, ssum3, ssq3, MN_D, D, 4);
  bn_coef<<<1, blk, 0, stream>>>(ssum3, ssq3, g3, be3, sc3, sh3, D, invM);

  // ---- GAT layer 1: act3 = bf16(elu(bn3(h3))); hgb = act3 @ Wg1 ----
  bn_elu_b16<<<1024, blk, 0, stream>>>(h3, sc3, sh3, actb, MN_D, D);
  gemm_bf16<<<gGAT, blk, 0, stream>>>(actb, Wg1h, hgb, n, HD, D, 8, rb);
  att_scores_bf16<<<n, blk, 0, stream>>>(hgb, as1, ad1, asrc, adst, n);
  aggregate_fused<<<n, blk, 0, stream>>>(hgb, row_start, csr_src, asrc, adst, bg1, agg);

  // ---- BN4 stats + coef + activation ----
  bn_stats<<<dim3(64, HD / 256), blk, 0, stream>>>(agg, n, HD, ssum4, ssq4);
  bn_coef<<<4, blk, 0, stream>>>(ssum4, ssq4, g4, be4, sc4, sh4, HD, invM);
  bn_elu_b16<<<2048, blk, 0, stream>>>(agg, sc4, sh4, actb, MN_HD, HD);

  // ---- GAT layer 2: hgb = act4 @ Wg2; out = aggregate + bg2 ----
  gemm_bf16<<<gGAT, blk, 0, stream>>>(actb, Wg2h, hgb, n, HD, HD, 8, rb);
  att_scores_bf16<<<n, blk, 0, stream>>>(hgb, as2, ad2, asrc, adst, n);
  aggregate_fused<<<n, blk, 0, stream>>>(hgb, row_start, csr_src, asrc, adst, bg2, out);
}

// Round 13
// 534.704 us; speedup vs baseline: 1.0713x; 1.0490x over previous
//
#include <hip/hip_runtime.h>
#include <hip/hip_bf16.h>

typedef __attribute__((ext_vector_type(8))) short short8v;
typedef __attribute__((ext_vector_type(4))) float f32x4;

__device__ inline float b2f(ushort u) {
  union { uint i; float f; } c;
  c.i = (uint)u << 16;
  return c.f;
}
__device__ inline ushort f2b(float f) {
  __hip_bfloat16 h = __float2bfloat16(f);
  return *(ushort*)&h;
}

typedef __attribute__((address_space(1))) const unsigned int guint;
typedef __attribute__((address_space(3))) unsigned int luint;
__device__ __forceinline__ void gload16(const void* g, void* l) {
  __builtin_amdgcn_global_load_lds((guint*)g, (luint*)l, 16, 0, 0);
}

// ===== MLP MFMA GEMM: A fp32 reg-prefetched (+BN fold), B dbuf gload_lds =====
// C = act(A)[M,K] @ B[N,Kp]^T, partials P[z][M][N]. grid = nc*nr*nz (%8==0).
// SPLIT: 3-term bf16 split (hi=trunc); !SPLIT: 1-term RNE bf16.
template <bool BN, bool ALIGNED, bool SPLIT>
__global__ __launch_bounds__(256) void gemm_bn(
    const float* __restrict__ A, const __hip_bfloat16* __restrict__ Bh,
    const __hip_bfloat16* __restrict__ Bl, const float* __restrict__ sc,
    const float* __restrict__ sh, float* __restrict__ P, int M, int N, int K,
    int Kp, int nc, int nr, int nz) {
  __shared__ ushort Ash[128][40];
  __shared__ ushort Asl[SPLIT ? 128 : 1][40];
  __shared__ ushort Bs2[2][128][32];
  __shared__ ushort Bl2[SPLIT ? 2 : 1][128][32];
  const int nwg = gridDim.x;
  const int b = blockIdx.x;
  const int l = (b & 7) * (nwg >> 3) + (b >> 3);
  const int cb = l % nc;
  const int rr = (l / nc) % nr;
  const int z = l / (nc * nr);

  const int tid = threadIdx.x;
  const int lane = tid & 63;
  const int w = tid >> 6, wr = w >> 1, wc = w & 1;
  const int brow = rr * 128, bcol = cb * 128;
  const int l15 = lane & 15, koff = (lane >> 4) * 8;
  const int arow = tid >> 1, aseg = (tid & 1) * 16;
  const int srow = tid >> 2, sseg = (tid & 3) * 8;
  const int nK = (K + 31) >> 5;
  const int ks0 = (nK * z) / nz, ks1 = (nK * (z + 1)) / nz;

  f32x4 acc[4][4] = {};

  const int ar = brow + arow;
  const bool arv = ar < M;
  const float* Arow = A + (long)ar * K;
  const ushort* gBh0 = (const ushort*)Bh + (long)(bcol + srow) * Kp + sseg;
  const ushort* gBh1 = (const ushort*)Bh + (long)(bcol + 64 + srow) * Kp + sseg;
  const ushort* gBl0 = SPLIT ? (const ushort*)Bl + (long)(bcol + srow) * Kp + sseg : nullptr;
  const ushort* gBl1 = SPLIT ? (const ushort*)Bl + (long)(bcol + 64 + srow) * Kp + sseg : nullptr;
  const int lo0 = (w * 64) << 3;
  const int lo1 = (256 + w * 64) << 3;

  float av[16];
  auto loadAv = [&](int ks) {
    const int kb = (ks << 5) + aseg;
    if (arv) {
      if (ALIGNED) {
        const float4* ap = (const float4*)(Arow + kb);
#pragma unroll
        for (int q = 0; q < 4; ++q) {
          float4 f = ap[q];
          av[q * 4 + 0] = f.x;
          av[q * 4 + 1] = f.y;
          av[q * 4 + 2] = f.z;
          av[q * 4 + 3] = f.w;
        }
      } else {
        if (kb + 16 <= K) {
#pragma unroll
          for (int j = 0; j < 16; ++j) av[j] = Arow[kb + j];
        } else {
#pragma unroll
          for (int j = 0; j < 16; ++j) av[j] = (kb + j < K) ? Arow[kb + j] : 0.f;
        }
      }
    } else {
#pragma unroll
      for (int j = 0; j < 16; ++j) av[j] = 0.f;
    }
  };

  if (ks0 < ks1) {
    loadAv(ks0);
    const int k0 = ks0 << 5;
    gload16(gBh0 + k0, &Bs2[0][0][0] + lo0);
    gload16(gBh1 + k0, &Bs2[0][0][0] + lo1);
    if (SPLIT) {
      gload16(gBl0 + k0, &Bl2[0][0][0] + lo0);
      gload16(gBl1 + k0, &Bl2[0][0][0] + lo1);
    }
  }

  for (int ks = ks0; ks < ks1; ++ks) {
    const int cur = (ks - ks0) & 1;
    const int kbase = (ks << 5) + aseg;
    if (BN && arv) {
#pragma unroll
      for (int q = 0; q < 4; ++q) {
        float4 c4 = *(const float4*)(sc + kbase + q * 4);
        float4 h4 = *(const float4*)(sh + kbase + q * 4);
        float* a4 = &av[q * 4];
        a4[0] = fmaf(a4[0], c4.x, h4.x);
        a4[1] = fmaf(a4[1], c4.y, h4.y);
        a4[2] = fmaf(a4[2], c4.z, h4.z);
        a4[3] = fmaf(a4[3], c4.w, h4.w);
      }
#pragma unroll
      for (int j = 0; j < 16; ++j) {
        float v = av[j];
        av[j] = v > 0.f ? v : (__expf(v) - 1.f);
      }
    }
    short8v ah0, ah1, al0, al1;
    if (SPLIT) {
#pragma unroll
      for (int j = 0; j < 8; ++j) {
        {
          uint u = __float_as_uint(av[j]);
          ah0[j] = (short)(u >> 16);
          al0[j] = (short)f2b(av[j] - __uint_as_float(u & 0xFFFF0000u));
        }
        {
          uint u = __float_as_uint(av[j + 8]);
          ah1[j] = (short)(u >> 16);
          al1[j] = (short)f2b(av[j + 8] - __uint_as_float(u & 0xFFFF0000u));
        }
      }
    } else {
#pragma unroll
      for (int j = 0; j < 8; ++j) {
        ah0[j] = (short)f2b(av[j]);
        ah1[j] = (short)f2b(av[j + 8]);
      }
    }
    __syncthreads();  // bar1: B(cur) landed (issued prev iter); prev reads done
    *(short8v*)&Ash[arow][aseg] = ah0;
    *(short8v*)&Ash[arow][aseg + 8] = ah1;
    if (SPLIT) {
      *(short8v*)&Asl[arow][aseg] = al0;
      *(short8v*)&Asl[arow][aseg + 8] = al1;
    }
    __syncthreads();  // bar2: A visible
    if (ks + 1 < ks1) {  // issue next-iter loads; drain at next bar1
      const int k0n = (ks + 1) << 5;
      const int nxt = cur ^ 1;
      gload16(gBh0 + k0n, &Bs2[nxt][0][0] + lo0);
      gload16(gBh1 + k0n, &Bs2[nxt][0][0] + lo1);
      if (SPLIT) {
        gload16(gBl0 + k0n, &Bl2[nxt][0][0] + lo0);
        gload16(gBl1 + k0n, &Bl2[nxt][0][0] + lo1);
      }
      loadAv(ks + 1);
    }
    short8v bfh[4], bfl[4];
#pragma unroll
    for (int nn = 0; nn < 4; ++nn) {
      bfh[nn] = *(const short8v*)&Bs2[cur][wc * 64 + nn * 16 + l15][koff];
      if (SPLIT) bfl[nn] = *(const short8v*)&Bl2[cur][wc * 64 + nn * 16 + l15][koff];
    }
#pragma unroll
    for (int m = 0; m < 4; ++m) {
      short8v afh = *(const short8v*)&Ash[wr * 64 + m * 16 + l15][koff];
      short8v afl;
      if (SPLIT) afl = *(const short8v*)&Asl[wr * 64 + m * 16 + l15][koff];
#pragma unroll
      for (int nn = 0; nn < 4; ++nn) {
        acc[m][nn] = __builtin_amdgcn_mfma_f32_16x16x32_bf16(afh, bfh[nn], acc[m][nn], 0, 0, 0);
        if (SPLIT) {
          acc[m][nn] = __builtin_amdgcn_mfma_f32_16x16x32_bf16(afh, bfl[nn], acc[m][nn], 0, 0, 0);
          acc[m][nn] = __builtin_amdgcn_mfma_f32_16x16x32_bf16(afl, bfh[nn], acc[m][nn], 0, 0, 0);
        }
      }
    }
  }

  float* outp = P + (long)z * M * N;
#pragma unroll
  for (int m = 0; m < 4; ++m) {
#pragma unroll
    for (int nn = 0; nn < 4; ++nn) {
      int col = bcol + wc * 64 + nn * 16 + l15;
#pragma unroll
      for (int r = 0; r < 4; ++r) {
        int row = brow + wr * 64 + m * 16 + (lane >> 4) * 4 + r;
        if (row < M) outp[(long)row * N + col] = acc[m][nn][r];
      }
    }
  }
}

// ===== pure bf16 MFMA GEMM (GAT layers), single-barrier double-buffer ========
__global__ __launch_bounds__(256) void gemm_bf16(
    const ushort* __restrict__ A, const __hip_bfloat16* __restrict__ B,
    ushort* __restrict__ C, int M, int N, int K, int nc, int nr) {
  __shared__ ushort A2[2][128][32];
  __shared__ ushort B2[2][128][32];
  const int nwg = gridDim.x;
  const int b = blockIdx.x;
  const int l = (b & 7) * (nwg >> 3) + (b >> 3);
  const int cb = l % nc;
  const int rr = l / nc;

  const int tid = threadIdx.x;
  const int lane = tid & 63;
  const int w = tid >> 6, wr = w >> 1, wc = w & 1;
  const int brow = rr * 128, bcol = cb * 128;
  const int l15 = lane & 15, koff = (lane >> 4) * 8;
  const int srow = tid >> 2, sseg = (tid & 3) * 8;
  const int nK = K >> 5;

  f32x4 acc[4][4] = {};

  const ushort* gA0 = A + (long)(brow + srow) * K + sseg;
  const ushort* gA1 = A + (long)(brow + 64 + srow) * K + sseg;
  const ushort* gB0 = (const ushort*)B + (long)(bcol + srow) * K + sseg;
  const ushort* gB1 = (const ushort*)B + (long)(bcol + 64 + srow) * K + sseg;
  const int lo0 = (w * 64) << 3;
  const int lo1 = (256 + w * 64) << 3;

  gload16(gA0, &A2[0][0][0] + lo0);
  gload16(gA1, &A2[0][0][0] + lo1);
  gload16(gB0, &B2[0][0][0] + lo0);
  gload16(gB1, &B2[0][0][0] + lo1);

  for (int ks = 0; ks < nK; ++ks) {
    const int cur = ks & 1;
    __syncthreads();  // buf[cur] landed; prev reads of buf[cur^1] done
    if (ks + 1 < nK) {
      const int k0n = (ks + 1) << 5;
      const int nxt = cur ^ 1;
      gload16(gA0 + k0n, &A2[nxt][0][0] + lo0);
      gload16(gA1 + k0n, &A2[nxt][0][0] + lo1);
      gload16(gB0 + k0n, &B2[nxt][0][0] + lo0);
      gload16(gB1 + k0n, &B2[nxt][0][0] + lo1);
    }
    short8v bf[4];
#pragma unroll
    for (int nn = 0; nn < 4; ++nn)
      bf[nn] = *(const short8v*)&B2[cur][wc * 64 + nn * 16 + l15][koff];
#pragma unroll
    for (int m = 0; m < 4; ++m) {
      short8v af = *(const short8v*)&A2[cur][wr * 64 + m * 16 + l15][koff];
#pragma unroll
      for (int nn = 0; nn < 4; ++nn)
        acc[m][nn] = __builtin_amdgcn_mfma_f32_16x16x32_bf16(af, bf[nn], acc[m][nn], 0, 0, 0);
    }
  }

#pragma unroll
  for (int m = 0; m < 4; ++m) {
#pragma unroll
    for (int nn = 0; nn < 4; ++nn) {
      int col = bcol + wc * 64 + nn * 16 + l15;
#pragma unroll
      for (int r = 0; r < 4; ++r) {
        int row = brow + wr * 64 + m * 16 + (lane >> 4) * 4 + r;
        if (row < M) C[(long)row * N + col] = f2b(acc[m][nn][r]);
      }
    }
  }
}

// ===== BN+ELU -> bf16 activation pass ========================================
__global__ __launch_bounds__(256) void bn_elu_b16(
    const float* __restrict__ h, const float* __restrict__ sc,
    const float* __restrict__ sh, ushort* __restrict__ o, long MN, int N) {
  long nq = MN >> 2;
  for (long q = blockIdx.x * 256LL + threadIdx.x; q < nq;
       q += (long)gridDim.x * 256LL) {
    long i = q << 2;
    int col = (int)(i % N);
    float4 v = *(const float4*)(h + i);
    float4 c = *(const float4*)(sc + col);
    float4 s = *(const float4*)(sh + col);
    float a0 = fmaf(v.x, c.x, s.x);
    float a1 = fmaf(v.y, c.y, s.y);
    float a2 = fmaf(v.z, c.z, s.z);
    float a3 = fmaf(v.w, c.w, s.w);
    a0 = a0 > 0.f ? a0 : (__expf(a0) - 1.f);
    a1 = a1 > 0.f ? a1 : (__expf(a1) - 1.f);
    a2 = a2 > 0.f ? a2 : (__expf(a2) - 1.f);
    a3 = a3 > 0.f ? a3 : (__expf(a3) - 1.f);
    ushort4 r;
    r.x = f2b(a0);
    r.y = f2b(a1);
    r.z = f2b(a2);
    r.w = f2b(a3);
    *(ushort4*)(o + i) = r;
  }
}

// ===== reduce partials (+bias) (+batch stats) ================================
template <bool BIAS, bool STATS>
__global__ __launch_bounds__(256) void reduce_post(
    const float* __restrict__ P, const float* __restrict__ bias,
    float* __restrict__ C, float* __restrict__ osum, float* __restrict__ osq,
    long MN, int N, int Z) {
  const int col = (int)((blockIdx.x * 256 + threadIdx.x) % N);
  const float bv = BIAS ? bias[col] : 0.f;
  float ps = 0.f, pq = 0.f;
  for (long i = blockIdx.x * 256LL + threadIdx.x; i < MN;
       i += (long)gridDim.x * 256LL) {
    float s = bv;
    for (int zz = 0; zz < Z; ++zz) s += P[(long)zz * MN + i];
    C[i] = s;
    if (STATS) {
      ps += s;
      pq += s * s;
    }
  }
  if (STATS) {
    atomicAdd(&osum[col], ps);
    atomicAdd(&osq[col], pq);
  }
}

// ===== bn coefficients =======================================================
__global__ __launch_bounds__(256) void bn_coef(
    const float* __restrict__ ssum, const float* __restrict__ ssq,
    const float* __restrict__ g, const float* __restrict__ be,
    float* __restrict__ sc, float* __restrict__ sh, int N, float invM) {
  int c = blockIdx.x * 256 + threadIdx.x;
  if (c >= N) return;
  float mean = ssum[c] * invM;
  float var = ssq[c] * invM - mean * mean;
  float s = rsqrtf(var + 1e-5f) * g[c];
  sc[c] = s;
  sh[c] = be[c] - mean * s;
}

// ===== tiled transpose + bf16 split ==========================================
template <bool LO>
__global__ __launch_bounds__(256) void trans_split(
    const float* __restrict__ W, __hip_bfloat16* __restrict__ Oh,
    __hip_bfloat16* __restrict__ Ol, int K, int N, int Kp) {
  __shared__ float tile[64][65];
  const int k0 = blockIdx.x * 64, n0 = blockIdx.y * 64;
  const int tx = threadIdx.x & 63, ty = threadIdx.x >> 6;
#pragma unroll
  for (int j = 0; j < 16; ++j) {
    int r = ty * 16 + j;
    int k = k0 + r;
    tile[r][tx] = (k < K) ? W[(long)k * N + n0 + tx] : 0.f;
  }
  __syncthreads();
#pragma unroll
  for (int j = 0; j < 16; ++j) {
    int a = ty * 16 + j;
    float v = tile[tx][a];
    long o = (long)(n0 + a) * Kp + k0 + tx;
    if (LO) {
      uint u = __float_as_uint(v);
      ushort hu = (ushort)(u >> 16);
      Oh[o] = *(__hip_bfloat16*)&hu;
      ushort lu = f2b(v - __uint_as_float(u & 0xFFFF0000u));
      Ol[o] = *(__hip_bfloat16*)&lu;
    } else {
      ushort hu = f2b(v);
      Oh[o] = *(__hip_bfloat16*)&hu;
    }
  }
}

// ===== BatchNorm stats (for BN4 on agg) ======================================
__global__ __launch_bounds__(256) void bn_stats(
    const float* __restrict__ h, int M, int N, float* __restrict__ sum,
    float* __restrict__ sumsq) {
  int col = blockIdx.y * 256 + threadIdx.x;
  float s = 0.f, sq = 0.f;
  for (int r = blockIdx.x; r < M; r += gridDim.x) {
    float v = h[(long)r * N + col];
    s += v;
    sq += v * v;
  }
  atomicAdd(&sum[col], s);
  atomicAdd(&sumsq[col], sq);
}

// ===== GAT attention scores from bf16 features ===============================
__global__ __launch_bounds__(256) void att_scores_bf16(
    const ushort* __restrict__ hgb, const float* __restrict__ att_s,
    const float* __restrict__ att_d, float* __restrict__ a_src,
    float* __restrict__ a_dst, int n) {
  int node = blockIdx.x;
  int h = threadIdx.x >> 6, lane = threadIdx.x & 63;
  int c = lane * 4;
  ushort4 hv = *(const ushort4*)(hgb + (long)node * 1024 + h * 256 + c);
  float4 as = *(const float4*)(att_s + h * 256 + c);
  float4 ad = *(const float4*)(att_d + h * 256 + c);
  float x0 = b2f(hv.x), x1 = b2f(hv.y), x2 = b2f(hv.z), x3 = b2f(hv.w);
  float ss = x0 * as.x + x1 * as.y + x2 * as.z + x3 * as.w;
  float sd = x0 * ad.x + x1 * ad.y + x2 * ad.z + x3 * ad.w;
#pragma unroll
  for (int off = 32; off; off >>= 1) {
    ss += __shfl_down(ss, off);
    sd += __shfl_down(sd, off);
  }
  if (lane == 0) {
    a_src[node * 4 + h] = ss;
    a_dst[node * 4 + h] = sd;
  }
}

// ===== CSR build =============================================================
__global__ __launch_bounds__(256) void deg_count(
    const int* __restrict__ srcA, const int* __restrict__ dstA,
    int* __restrict__ deg, int n, int E0, int E) {
  int e = blockIdx.x * blockDim.x + threadIdx.x;
  if (e >= E) return;
  int d;
  if (e < E0) {
    int s = srcA[e];
    d = dstA[e];
    if (s == d) d = (d + 1) % n;
  } else {
    d = e - E0;
  }
  atomicAdd(&deg[d], 1);
}

__global__ __launch_bounds__(256) void scan_rows(
    const int* __restrict__ deg, int* __restrict__ row_start, int n) {
  __shared__ int sums[256];
  int t = threadIdx.x;
  int chunk = (n + 255) / 256;
  int start = t * chunk, end = min(start + chunk, n);
  int s = 0;
  for (int i = start; i < end; ++i) s += deg[i];
  sums[t] = s;
  __syncthreads();
  for (int off = 1; off < 256; off <<= 1) {
    int v = (t >= off) ? sums[t - off] : 0;
    __syncthreads();
    sums[t] += v;
    __syncthreads();
  }
  int run = (t == 0) ? 0 : sums[t - 1];
  for (int i = start; i < end; ++i) {
    row_start[i] = run;
    run += deg[i];
  }
  if (t == 255) row_start[n] = run;
}

__global__ __launch_bounds__(256) void scatter_edges(
    const int* __restrict__ srcA, const int* __restrict__ dstA,
    int* __restrict__ cursor, int* __restrict__ csr_src, int n, int E0, int E) {
  int e = blockIdx.x * blockDim.x + threadIdx.x;
  if (e >= E) return;
  int s, d;
  if (e < E0) {
    s = srcA[e];
    d = dstA[e];
    if (s == d) d = (d + 1) % n;
  } else {
    s = d = e - E0;
  }
  int pos = atomicAdd(&cursor[d], 1);
  csr_src[pos] = s;
}

// ===== fused softmax + gather aggregation ====================================
__global__ __launch_bounds__(256) void aggregate_fused(
    const ushort* __restrict__ hgb, const int* __restrict__ row_start,
    const int* __restrict__ csr_src, const float* __restrict__ a_src,
    const float* __restrict__ a_dst, const float* __restrict__ bias,
    float* __restrict__ out) {
  int d = blockIdx.x;
  int t = threadIdx.x;
  int hh = t >> 6;
  int off = hh * 256 + (t & 63) * 4;
  int p0 = row_start[d], p1 = row_start[d + 1];
  float adv = a_dst[d * 4 + hh];
  float den = 1e-16f;
  float4 acc = {0.f, 0.f, 0.f, 0.f};
  for (int p = p0; p < p1; ++p) {
    int s = csr_src[p];
    float v = a_src[s * 4 + hh] + adv;
    v = v > 0.f ? v : 0.2f * v;
    float ex = __expf(v);
    den += ex;
    ushort4 hv = *(const ushort4*)(hgb + (long)s * 1024 + off);
    acc.x += ex * b2f(hv.x);
    acc.y += ex * b2f(hv.y);
    acc.z += ex * b2f(hv.z);
    acc.w += ex * b2f(hv.w);
  }
  float rden = 1.f / den;
  float4 bv = *(const float4*)(bias + off);
  float4 o;
  o.x = bv.x + acc.x * rden;
  o.y = bv.y + acc.y * rden;
  o.z = bv.z + acc.z * rden;
  o.w = bv.w + acc.w * rden;
  *(float4*)(out + (long)d * 1024 + off) = o;
}

extern "C" void kernel_launch(void* const* d_in, const int* in_sizes, int n_in,
                              void* d_out, int out_size, void* d_ws,
                              size_t ws_size, hipStream_t stream) {
  const float* x = (const float*)d_in[0];
  const int* edges = (const int*)d_in[1];
  const float* W1 = (const float*)d_in[2];
  const float* b1 = (const float*)d_in[3];
  const float* W2 = (const float*)d_in[4];
  const float* b2 = (const float*)d_in[5];
  const float* W3 = (const float*)d_in[6];
  const float* b3 = (const float*)d_in[7];
  const float* g1 = (const float*)d_in[8];
  const float* be1 = (const float*)d_in[9];
  const float* g2 = (const float*)d_in[10];
  const float* be2 = (const float*)d_in[11];
  const float* g3 = (const float*)d_in[12];
  const float* be3 = (const float*)d_in[13];
  const float* g4 = (const float*)d_in[14];
  const float* be4 = (const float*)d_in[15];
  const float* Wg1 = (const float*)d_in[16];
  const float* as1 = (const float*)d_in[17];
  const float* ad1 = (const float*)d_in[18];
  const float* bg1 = (const float*)d_in[19];
  const float* Wg2 = (const float*)d_in[20];
  const float* as2 = (const float*)d_in[21];
  const float* ad2 = (const float*)d_in[22];
  const float* bg2 = (const float*)d_in[23];
  float* out = (float*)d_out;

  const int n = 10000, E0 = 160000, E = 170000;
  const int F = 2613, Fp = 2624, D = 256, HD = 1024;
  const int* srcA = edges;
  const int* dstA = edges + E0;

  uint8_t* p = (uint8_t*)d_ws;
  auto alloc = [&](size_t bytes) -> void* {
    void* r = (void*)p;
    p += (bytes + 255) & ~(size_t)255;
    return r;
  };
  float* h1 = (float*)alloc((size_t)n * D * 4);
  float* h2 = (float*)alloc((size_t)n * D * 4);
  float* h3 = (float*)alloc((size_t)n * D * 4);
  float* agg = (float*)alloc((size_t)n * HD * 4);
  float* pbuf = (float*)alloc((size_t)4 * n * D * 4);  // Z<=4 partials
  ushort* hgb = (ushort*)alloc((size_t)n * HD * 2);    // bf16 GAT features
  ushort* actb = (ushort*)alloc((size_t)n * HD * 2);   // bf16 activations
  __hip_bfloat16* W1h = (__hip_bfloat16*)alloc((size_t)D * Fp * 2);
  __hip_bfloat16* W2h = (__hip_bfloat16*)alloc((size_t)D * D * 2);
  __hip_bfloat16* W2l = (__hip_bfloat16*)alloc((size_t)D * D * 2);
  __hip_bfloat16* W3h = (__hip_bfloat16*)alloc((size_t)D * D * 2);
  __hip_bfloat16* W3l = (__hip_bfloat16*)alloc((size_t)D * D * 2);
  __hip_bfloat16* Wg1h = (__hip_bfloat16*)alloc((size_t)HD * D * 2);
  __hip_bfloat16* Wg2h = (__hip_bfloat16*)alloc((size_t)HD * HD * 2);
  float* asrc = (float*)alloc((size_t)n * 4 * 4);
  float* adst = (float*)alloc((size_t)n * 4 * 4);
  float* sc1 = (float*)alloc(D * 4);
  float* sh1 = (float*)alloc(D * 4);
  float* sc2 = (float*)alloc(D * 4);
  float* sh2 = (float*)alloc(D * 4);
  float* sc3 = (float*)alloc(D * 4);
  float* sh3 = (float*)alloc(D * 4);
  float* sc4 = (float*)alloc(HD * 4);
  float* sh4 = (float*)alloc(HD * 4);
  int* row_start = (int*)alloc((size_t)(n + 1) * 4);
  int* cursor = (int*)alloc((size_t)n * 4);
  int* csr_src = (int*)alloc((size_t)E * 4);
  // ---- contiguous zero block (stats + deg) ----
  uint8_t* z0 = p;
  float* ssum1 = (float*)alloc(D * 4);
  float* ssq1 = (float*)alloc(D * 4);
  float* ssum2 = (float*)alloc(D * 4);
  float* ssq2 = (float*)alloc(D * 4);
  float* ssum3 = (float*)alloc(D * 4);
  float* ssq3 = (float*)alloc(D * 4);
  float* ssum4 = (float*)alloc(HD * 4);
  float* ssq4 = (float*)alloc(HD * 4);
  int* deg = (int*)alloc((size_t)n * 4);
  size_t zbytes = (size_t)(p - z0);

  dim3 blk(256);
  const int rb = (n + 127) / 128;  // 79
  const int eb = (E + 255) / 256;
  const long MN_D = (long)n * D;
  const long MN_HD = (long)n * HD;
  const float invM = 1.f / (float)n;
  const int gMLP = 2 * rb * 4;  // 632  (Z=4)
  const int gGAT = 8 * rb;      // 632

  hipMemsetAsync(z0, 0, zbytes, stream);

  // ---- CSR build ----
  deg_count<<<eb, blk, 0, stream>>>(srcA, dstA, deg, n, E0, E);
  scan_rows<<<1, blk, 0, stream>>>(deg, row_start, n);
  hipMemcpyAsync(cursor, row_start, n * sizeof(int), hipMemcpyDeviceToDevice, stream);
  scatter_edges<<<eb, blk, 0, stream>>>(srcA, dstA, cursor, csr_src, n, E0, E);

  // ---- weight transpose+split ----
  trans_split<false><<<dim3(Fp / 64, D / 64), blk, 0, stream>>>(W1, W1h, nullptr, F, D, Fp);
  trans_split<true><<<dim3(D / 64, D / 64), blk, 0, stream>>>(W2, W2h, W2l, D, D, D);
  trans_split<true><<<dim3(D / 64, D / 64), blk, 0, stream>>>(W3, W3h, W3l, D, D, D);
  trans_split<false><<<dim3(D / 64, HD / 64), blk, 0, stream>>>(Wg1, Wg1h, nullptr, D, HD, D);
  trans_split<false><<<dim3(HD / 64, HD / 64), blk, 0, stream>>>(Wg2, Wg2h, nullptr, HD, HD, HD);

  // ---- MLP layer 1: h1 = x@W1 + b1 (raw); stats1  [1-term bf16, Z=4] ----
  gemm_bn<false, false, false><<<gMLP, blk, 0, stream>>>(
      x, W1h, nullptr, nullptr, nullptr, pbuf, n, D, F, Fp, 2, rb, 4);
  reduce_post<true, true><<<512, blk, 0, stream>>>(pbuf, b1, h1, ssum1, ssq1, MN_D, D, 4);
  bn_coef<<<1, blk, 0, stream>>>(ssum1, ssq1, g1, be1, sc1, sh1, D, invM);

  // ---- MLP layer 2  [3-term, Z=4, BN1 fused] ----
  gemm_bn<true, true, true><<<gMLP, blk, 0, stream>>>(
      h1, W2h, W2l, sc1, sh1, pbuf, n, D, D, D, 2, rb, 4);
  reduce_post<true, true><<<512, blk, 0, stream>>>(pbuf, b2, h2, ssum2, ssq2, MN_D, D, 4);
  bn_coef<<<1, blk, 0, stream>>>(ssum2, ssq2, g2, be2, sc2, sh2, D, invM);

  // ---- MLP layer 3  [3-term, Z=4, BN2 fused] ----
  gemm_bn<true, true, true><<<gMLP, blk, 0, stream>>>(
      h2, W3h, W3l, sc2, sh2, pbuf, n, D, D, D, 2, rb, 4);
  reduce_post<true, true><<<512, blk, 0, stream>>>(pbuf, b3, h3, ssum3, ssq3, MN_D, D, 4);
  bn_coef<<<1, blk, 0, stream>>>(ssum3, ssq3, g3, be3, sc3, sh3, D, invM);

  // ---- GAT layer 1: act3 = bf16(elu(bn3(h3))); hgb = act3 @ Wg1 ----
  bn_elu_b16<<<1024, blk, 0, stream>>>(h3, sc3, sh3, actb, MN_D, D);
  gemm_bf16<<<gGAT, blk, 0, stream>>>(actb, Wg1h, hgb, n, HD, D, 8, rb);
  att_scores_bf16<<<n, blk, 0, stream>>>(hgb, as1, ad1, asrc, adst, n);
  aggregate_fused<<<n, blk, 0, stream>>>(hgb, row_start, csr_src, asrc, adst, bg1, agg);

  // ---- BN4 stats + coef + activation ----
  bn_stats<<<dim3(64, HD / 256), blk, 0, stream>>>(agg, n, HD, ssum4, ssq4);
  bn_coef<<<4, blk, 0, stream>>>(ssum4, ssq4, g4, be4, sc4, sh4, HD, invM);
  bn_elu_b16<<<2048, blk, 0, stream>>>(agg, sc4, sh4, actb, MN_HD, HD);

  // ---- GAT layer 2: hgb = act4 @ Wg2; out = aggregate + bg2 ----
  gemm_bf16<<<gGAT, blk, 0, stream>>>(actb, Wg2h, hgb, n, HD, HD, 8, rb);
  att_scores_bf16<<<n, blk, 0, stream>>>(hgb, as2, ad2, asrc, adst, n);
  aggregate_fused<<<n, blk, 0, stream>>>(hgb, row_start, csr_src, asrc, adst, bg2, out);
}